// Round 4
// baseline (289.477 us; speedup 1.0000x reference)
//
#include <hip/hip_runtime.h>
#include <hip/hip_cooperative_groups.h>
#include <math.h>

// Network_22892175688023 — round 4: single cooperative kernel, 3 grid syncs.
// P0 prep weight planes + P1 enc1/stats | sync | P2 bn1+enc2/stats | sync |
// P3 bn2+gate->bc | sync | gen (blocks 0-63, 16 rows each, full MANN chain).

namespace cg = cooperative_groups;

#define DIN 103
#define NE  8
#define HH  256
#define DOUT 51
#define EPSBN 1e-5f

typedef __attribute__((ext_vector_type(8))) short bf16x8;
typedef __attribute__((ext_vector_type(4))) float f32x4;
typedef __attribute__((ext_vector_type(8))) unsigned short us8;

__device__ __forceinline__ float eluf(float v) { return v > 0.f ? v : (expf(v) - 1.f); }
__device__ __forceinline__ unsigned short bf16h(float f) {
  unsigned u = __float_as_uint(f);
  u += 0x7FFFu + ((u >> 16) & 1u);
  return (unsigned short)(u >> 16);
}
__device__ __forceinline__ float bf16f(unsigned short h) { return __uint_as_float(((unsigned)h) << 16); }
__device__ __forceinline__ void split_bf16(float v, unsigned short& h, unsigned short& l) {
  h = bf16h(v);
  l = bf16h(v - bf16f(h));
}
#define MFMA __builtin_amdgcn_mfma_f32_16x16x32_bf16

// ---- LDS phase structs (union'd) ----
struct P1SM { float w1L[64 * DIN]; float xr[8][104]; float hb[8][64]; };
struct P2SM { float w2T[64 * 32]; float red[128]; float sc1[64]; float sh1[64];
              float h1b[8][64]; float hb2[8][32]; };
struct P3SM { float gw1L[64 * 33]; float gw2L[64 * 65]; float gw3L[8 * 65];
              float red2[64]; float sc2[32]; float sh2[32];
              float gb1L[64]; float gb2L[64]; float gb3L[8];
              float latb[8][32]; float g1b[8][64]; float g2b[8][64]; };
struct GenSM {
  unsigned short xfH[2048], xfL[2048];     // x fragments [4kc][512]
  unsigned short a1H[4096], a1L[4096];     // h1 act fragments [8kc][512]
  unsigned short a2H[4096], a2L[4096];     // h2 act fragments [8kc][512]
  float bcL[16][NE];
  float eb1L[NE][HH], eb2L[NE][HH];
  float eb3L[NE][64];
  float p3u[16][64];
};
union __align__(16) SMU { P1SM p1; P2SM p2; P3SM p3; GenSM g; };

// ---- ws layout (floats): slots1[128][128]@0 | slots2[128][64]@16384 |
// h1raw@24576 | h2raw@90112 | bc@122880 | E1H@131072 E1L@262144 |
// E2H@393216 E2L@655360 | E3H@917504 E3L@983040

__global__ __launch_bounds__(512, 4) void fused(
    const float* __restrict__ x,
    const float* __restrict__ w1, const float* __restrict__ b1,
    const float* __restrict__ gamma1, const float* __restrict__ beta1,
    const float* __restrict__ w2, const float* __restrict__ b2,
    const float* __restrict__ gamma2, const float* __restrict__ beta2,
    const float* __restrict__ gw1, const float* __restrict__ gb1,
    const float* __restrict__ gw2, const float* __restrict__ gb2,
    const float* __restrict__ gw3, const float* __restrict__ gb3,
    const float* __restrict__ ew1, const float* __restrict__ eb1,
    const float* __restrict__ ew2, const float* __restrict__ eb2,
    const float* __restrict__ ew3, const float* __restrict__ eb3,
    float* __restrict__ ws, float* __restrict__ out) {
  __shared__ SMU sm;
  cg::grid_group grid = cg::this_grid();
  const int bk = blockIdx.x, t = threadIdx.x;
  const int wv = t >> 6, l = t & 63;

  float* slots1 = ws;
  float* slots2 = ws + 16384;
  float* h1raw  = ws + 24576;
  float* h2raw  = ws + 90112;
  float* bc     = ws + 122880;
  unsigned short* E1H = (unsigned short*)(ws + 131072);
  unsigned short* E1L = (unsigned short*)(ws + 262144);
  unsigned short* E2H = (unsigned short*)(ws + 393216);
  unsigned short* E2L = (unsigned short*)(ws + 655360);
  unsigned short* E3H = (unsigned short*)(ws + 917504);
  unsigned short* E3L = (unsigned short*)(ws + 983040);

  // ================= P0: weights -> fragment-order bf16 hi/lo planes =================
  for (int G = bk * 512 + t; G < 114688; G += 65536) {
    int g = G >> 6, ll = G & 63;
    int c = ll & 15, q = ll >> 4;
    us8 H8, L8;
    if (g < 512) {                       // E1: g = (e*16+ns)*4+kc
      int kc = g & 3, ns = (g >> 2) & 15, e = g >> 6;
      int n = ns * 16 + c, k0 = kc * 32 + q * 8;
#pragma unroll
      for (int j = 0; j < 8; ++j) {
        int k = k0 + j;
        float v = (k < DIN) ? ew1[((size_t)e * DIN + k) * HH + n] : 0.f;
        unsigned short h, lo; split_bf16(v, h, lo); H8[j] = h; L8[j] = lo;
      }
      *(us8*)(E1H + (size_t)g * 512 + ll * 8) = H8;
      *(us8*)(E1L + (size_t)g * 512 + ll * 8) = L8;
    } else if (g < 1536) {               // E2: g2 = (e*16+ns)*8+kc
      int g2 = g - 512;
      int kc = g2 & 7, ns = (g2 >> 3) & 15, e = g2 >> 7;
      int n = ns * 16 + c, k0 = kc * 32 + q * 8;
#pragma unroll
      for (int j = 0; j < 8; ++j) {
        float v = ew2[((size_t)e * HH + k0 + j) * HH + n];
        unsigned short h, lo; split_bf16(v, h, lo); H8[j] = h; L8[j] = lo;
      }
      *(us8*)(E2H + (size_t)g2 * 512 + ll * 8) = H8;
      *(us8*)(E2L + (size_t)g2 * 512 + ll * 8) = L8;
    } else {                             // E3: g3 = (e*4+ns)*8+kc, N pad 51->64
      int g3 = g - 1536;
      int kc = g3 & 7, ns = (g3 >> 3) & 3, e = g3 >> 5;
      int n = ns * 16 + c, k0 = kc * 32 + q * 8;
#pragma unroll
      for (int j = 0; j < 8; ++j) {
        float v = (n < DOUT) ? ew3[((size_t)e * HH + k0 + j) * DOUT + n] : 0.f;
        unsigned short h, lo; split_bf16(v, h, lo); H8[j] = h; L8[j] = lo;
      }
      *(us8*)(E3H + (size_t)g3 * 512 + ll * 8) = H8;
      *(us8*)(E3L + (size_t)g3 * 512 + ll * 8) = L8;
    }
  }

  // ================= P1: enc layer 1 + stats1 (8 rows/block) =================
  {
    P1SM& S = sm.p1;
    int r0 = bk * 8;
    for (int i = t; i < 64 * DIN; i += 512) S.w1L[i] = w1[i];
    for (int i = t; i < 8 * 104; i += 512) {
      int r = i / 104, c2 = i - r * 104;
      float v = 0.f;
      if (c2 < DIN) { v = x[(size_t)(r0 + r) * DIN + c2]; if (c2 >= 100) v *= 100.f; }
      S.xr[r][c2] = v;
    }
    __syncthreads();
    {
      int r = t >> 6, j = t & 63;
      float acc = b1[j];
      for (int i = 0; i < DIN; ++i) acc = fmaf(S.xr[r][i], S.w1L[j * DIN + i], acc);
      S.hb[r][j] = acc;
      h1raw[(size_t)(r0 + r) * 64 + j] = acc;
    }
    __syncthreads();
    if (t < 64) {
      float s = 0.f, q = 0.f;
      for (int r = 0; r < 8; ++r) { float v = S.hb[r][t]; s += v; q += v * v; }
      slots1[bk * 128 + t] = s;
      slots1[bk * 128 + 64 + t] = q;
    }
  }
  grid.sync();

  // ================= P2: bn1+relu, enc layer 2 + stats2 =================
  {
    P2SM& S = sm.p2;
    int r0 = bk * 8;
    for (int i = t; i < 2048; i += 512) { int j = i >> 6, k = i & 63; S.w2T[k * 32 + j] = w2[i]; }
    if (t < 128) {
      float s = 0.f;
      for (int b = 0; b < 128; ++b) s += slots1[b * 128 + t];
      S.red[t] = s;
    }
    __syncthreads();
    if (t < 64) {
      float m = S.red[t] * (1.f / 1024.f);
      float v = S.red[64 + t] * (1.f / 1024.f) - m * m;
      float sc = gamma1[t] * rsqrtf(v + EPSBN);
      S.sc1[t] = sc; S.sh1[t] = beta1[t] - m * sc;
    }
    __syncthreads();
    {
      int r = t >> 6, j = t & 63;
      float raw = h1raw[(size_t)(r0 + r) * 64 + j];
      S.h1b[r][j] = fmaxf(fmaf(raw, S.sc1[j], S.sh1[j]), 0.f);
    }
    __syncthreads();
    if (t < 256) {
      int r = t >> 5, j = t & 31;
      float acc = b2[j];
      for (int k = 0; k < 64; ++k) acc = fmaf(S.h1b[r][k], S.w2T[k * 32 + j], acc);
      S.hb2[r][j] = acc;
      h2raw[(size_t)(r0 + r) * 32 + j] = acc;
    }
    __syncthreads();
    if (t < 32) {
      float s = 0.f, q = 0.f;
      for (int r = 0; r < 8; ++r) { float v = S.hb2[r][t]; s += v; q += v * v; }
      slots2[bk * 64 + t] = s;
      slots2[bk * 64 + 32 + t] = q;
    }
  }
  grid.sync();

  // ================= P3: bn2+relu, gating MLP -> bc =================
  {
    P3SM& S = sm.p3;
    int r0 = bk * 8;
    for (int i = t; i < 2048; i += 512) { int j = i >> 5, k = i & 31; S.gw1L[j * 33 + k] = gw1[i]; }
    for (int i = t; i < 4096; i += 512) { int j = i >> 6, k = i & 63; S.gw2L[j * 65 + k] = gw2[i]; }
    if (t < 512) { int j = t >> 6, k = t & 63; S.gw3L[j * 65 + k] = gw3[t]; }
    if (t < 64) { S.gb1L[t] = gb1[t]; S.gb2L[t] = gb2[t]; }
    if (t < 8) S.gb3L[t] = gb3[t];
    if (t < 64) {
      float s = 0.f;
      for (int b = 0; b < 128; ++b) s += slots2[b * 64 + t];
      S.red2[t] = s;
    }
    __syncthreads();
    if (t < 32) {
      float m = S.red2[t] * (1.f / 1024.f);
      float v = S.red2[32 + t] * (1.f / 1024.f) - m * m;
      float sc = gamma2[t] * rsqrtf(v + EPSBN);
      S.sc2[t] = sc; S.sh2[t] = beta2[t] - m * sc;
    }
    __syncthreads();
    if (t < 256) {
      int r = t >> 5, c2 = t & 31;
      float raw = h2raw[(size_t)(r0 + r) * 32 + c2];
      S.latb[r][c2] = fmaxf(fmaf(raw, S.sc2[c2], S.sh2[c2]), 0.f);
    }
    __syncthreads();
    {
      int r = wv;   // one wave per row
      float a1 = S.gb1L[l];
      for (int k = 0; k < 32; ++k) a1 = fmaf(S.gw1L[l * 33 + k], S.latb[r][k], a1);
      S.g1b[r][l] = eluf(a1);
      float a2 = S.gb2L[l];
      for (int k = 0; k < 64; ++k) a2 = fmaf(S.gw2L[l * 65 + k], S.g1b[r][k], a2);
      S.g2b[r][l] = eluf(a2);
      if (l < 8) {
        float a3 = S.gb3L[l];
        for (int k = 0; k < 64; ++k) a3 = fmaf(S.gw3L[l * 65 + k], S.g2b[r][k], a3);
        float mx = a3;
        mx = fmaxf(mx, __shfl_xor(mx, 1));
        mx = fmaxf(mx, __shfl_xor(mx, 2));
        mx = fmaxf(mx, __shfl_xor(mx, 4));
        float p = expf(a3 - mx);
        float sp = p;
        sp += __shfl_xor(sp, 1); sp += __shfl_xor(sp, 2); sp += __shfl_xor(sp, 4);
        bc[(size_t)(r0 + r) * 8 + l] = p / sp;
      }
    }
  }
  grid.sync();

  // ================= GEN: blocks 0-63, 16 rows each, full MANN chain =================
  if (bk < 64) {
    GenSM& S = sm.g;
    const int R0 = bk * 16;
    const int c = l & 15, quad = l >> 4;
    if (t < 128) S.bcL[t >> 3][t & 7] = bc[(size_t)(R0 + (t >> 3)) * 8 + (t & 7)];
    for (int i = t; i < 2048; i += 512) ((float*)S.eb1L)[i] = eb1[i];
    for (int i = t; i < 2048; i += 512) ((float*)S.eb2L)[i] = eb2[i];
    if (t < 512) { int e = t >> 6, n = t & 63; ((float*)S.eb3L)[t] = (n < DOUT) ? eb3[e * DOUT + n] : 0.f; }
    for (int tau = t; tau < 2048; tau += 512) {
      int kc = tau >> 9, rem = tau & 511;
      int lp = rem >> 3, j = rem & 7;
      int bl = lp & 15, q = lp >> 4;
      int k = kc * 32 + q * 8 + j;
      float v = 0.f;
      if (k < DIN) { v = x[(size_t)(R0 + bl) * DIN + k]; if (k >= 100) v *= 100.f; }
      unsigned short h, lo; split_bf16(v, h, lo);
      S.xfH[tau] = h; S.xfL[tau] = lo;
    }
    __syncthreads();

    // ---- stage 1: h1 = elu(sum_e bc*(xs@ew1_e + eb1_e)) ----
    {
      bf16x8 xh[4], xl[4];
#pragma unroll
      for (int kc = 0; kc < 4; ++kc) {
        xh[kc] = *(const bf16x8*)(S.xfH + kc * 512 + l * 8);
        xl[kc] = *(const bf16x8*)(S.xfL + kc * 512 + l * 8);
      }
      for (int nsi = 0; nsi < 2; ++nsi) {
        int ns = wv * 2 + nsi;
        f32x4 tot = {0.f, 0.f, 0.f, 0.f};
        for (int e = 0; e < NE; ++e) {
          f32x4 acc = {0.f, 0.f, 0.f, 0.f};
#pragma unroll
          for (int kc = 0; kc < 4; ++kc) {
            size_t bo = ((size_t)((e * 16 + ns) * 4 + kc)) * 512 + l * 8;
            bf16x8 bh = *(const bf16x8*)(E1H + bo);
            bf16x8 bl2 = *(const bf16x8*)(E1L + bo);
            acc = MFMA(xh[kc], bh, acc, 0, 0, 0);
            acc = MFMA(xl[kc], bh, acc, 0, 0, 0);
            acc = MFMA(xh[kc], bl2, acc, 0, 0, 0);
          }
#pragma unroll
          for (int r = 0; r < 4; ++r) tot[r] = fmaf(S.bcL[quad * 4 + r][e], acc[r], tot[r]);
        }
        int col = ns * 16 + c;
#pragma unroll
        for (int r = 0; r < 4; ++r) {
          float bb = 0.f;
#pragma unroll
          for (int e = 0; e < NE; ++e) bb = fmaf(S.bcL[quad * 4 + r][e], S.eb1L[e][col], bb);
          float v = eluf(tot[r] + bb);
          unsigned short h, lo; split_bf16(v, h, lo);
          int dst = (ns >> 1) * 512 + (((ns & 1) * 2 + (c >> 3)) * 16 + quad * 4 + r) * 8 + (c & 7);
          S.a1H[dst] = h; S.a1L[dst] = lo;
        }
      }
    }
    __syncthreads();

    // ---- stage 2: h2 = elu(sum_e bc*(h1@ew2_e + eb2_e)) ----
    {
      bf16x8 ah[8], al[8];
#pragma unroll
      for (int kc = 0; kc < 8; ++kc) {
        ah[kc] = *(const bf16x8*)(S.a1H + kc * 512 + l * 8);
        al[kc] = *(const bf16x8*)(S.a1L + kc * 512 + l * 8);
      }
      for (int nsi = 0; nsi < 2; ++nsi) {
        int ns = wv * 2 + nsi;
        f32x4 tot = {0.f, 0.f, 0.f, 0.f};
        for (int e = 0; e < NE; ++e) {
          f32x4 acc = {0.f, 0.f, 0.f, 0.f};
#pragma unroll
          for (int kc = 0; kc < 8; ++kc) {
            size_t bo = ((size_t)((e * 16 + ns) * 8 + kc)) * 512 + l * 8;
            bf16x8 bh = *(const bf16x8*)(E2H + bo);
            bf16x8 bl2 = *(const bf16x8*)(E2L + bo);
            acc = MFMA(ah[kc], bh, acc, 0, 0, 0);
            acc = MFMA(al[kc], bh, acc, 0, 0, 0);
            acc = MFMA(ah[kc], bl2, acc, 0, 0, 0);
          }
#pragma unroll
          for (int r = 0; r < 4; ++r) tot[r] = fmaf(S.bcL[quad * 4 + r][e], acc[r], tot[r]);
        }
        int col = ns * 16 + c;
#pragma unroll
        for (int r = 0; r < 4; ++r) {
          float bb = 0.f;
#pragma unroll
          for (int e = 0; e < NE; ++e) bb = fmaf(S.bcL[quad * 4 + r][e], S.eb2L[e][col], bb);
          float v = eluf(tot[r] + bb);
          unsigned short h, lo; split_bf16(v, h, lo);
          int dst = (ns >> 1) * 512 + (((ns & 1) * 2 + (c >> 3)) * 16 + quad * 4 + r) * 8 + (c & 7);
          S.a2H[dst] = h; S.a2L[dst] = lo;
        }
      }
    }
    __syncthreads();

    // ---- stage 3: out = sum_e bc*(h2@ew3_e + eb3_e)  (waves split experts) ----
    {
      bf16x8 ah[8], al[8];
#pragma unroll
      for (int kc = 0; kc < 8; ++kc) {
        ah[kc] = *(const bf16x8*)(S.a2H + kc * 512 + l * 8);
        al[kc] = *(const bf16x8*)(S.a2L + kc * 512 + l * 8);
      }
      int ns = wv & 3, eh = wv >> 2;
      f32x4 tot = {0.f, 0.f, 0.f, 0.f};
      for (int ei = 0; ei < 4; ++ei) {
        int e = eh * 4 + ei;
        f32x4 acc = {0.f, 0.f, 0.f, 0.f};
#pragma unroll
        for (int kc = 0; kc < 8; ++kc) {
          size_t bo = ((size_t)((e * 4 + ns) * 8 + kc)) * 512 + l * 8;
          bf16x8 bh = *(const bf16x8*)(E3H + bo);
          bf16x8 bl2 = *(const bf16x8*)(E3L + bo);
          acc = MFMA(ah[kc], bh, acc, 0, 0, 0);
          acc = MFMA(al[kc], bh, acc, 0, 0, 0);
          acc = MFMA(ah[kc], bl2, acc, 0, 0, 0);
        }
#pragma unroll
        for (int r = 0; r < 4; ++r) tot[r] = fmaf(S.bcL[quad * 4 + r][e], acc[r], tot[r]);
      }
      if (eh == 1) {
#pragma unroll
        for (int r = 0; r < 4; ++r) S.p3u[quad * 4 + r][ns * 16 + c] = tot[r];
      }
      __syncthreads();
      if (eh == 0) {
        int col = ns * 16 + c;
#pragma unroll
        for (int r = 0; r < 4; ++r) {
          float bb = 0.f;
#pragma unroll
          for (int e = 0; e < NE; ++e) bb = fmaf(S.bcL[quad * 4 + r][e], S.eb3L[e][col], bb);
          float v = tot[r] + S.p3u[quad * 4 + r][col] + bb;
          if (col < DOUT) out[(size_t)(R0 + quad * 4 + r) * DOUT + col] = v;
        }
      }
    }
  }
}

extern "C" void kernel_launch(void* const* d_in, const int* in_sizes, int n_in,
                              void* d_out, int out_size, void* d_ws, size_t ws_size,
                              hipStream_t stream) {
  const float* x      = (const float*)d_in[0];
  const float* w1     = (const float*)d_in[1];
  const float* b1     = (const float*)d_in[2];
  const float* gamma1 = (const float*)d_in[3];
  const float* beta1  = (const float*)d_in[4];
  const float* w2     = (const float*)d_in[5];
  const float* b2     = (const float*)d_in[6];
  const float* gamma2 = (const float*)d_in[7];
  const float* beta2  = (const float*)d_in[8];
  const float* gw1    = (const float*)d_in[9];
  const float* gb1    = (const float*)d_in[10];
  const float* gw2    = (const float*)d_in[11];
  const float* gb2    = (const float*)d_in[12];
  const float* gw3    = (const float*)d_in[13];
  const float* gb3    = (const float*)d_in[14];
  const float* ew1    = (const float*)d_in[15];
  const float* eb1    = (const float*)d_in[16];
  const float* ew2    = (const float*)d_in[17];
  const float* eb2    = (const float*)d_in[18];
  const float* ew3    = (const float*)d_in[19];
  const float* eb3    = (const float*)d_in[20];
  float* wsf  = (float*)d_ws;
  float* outp = (float*)d_out;

  void* args[] = {
    (void*)&x,
    (void*)&w1, (void*)&b1, (void*)&gamma1, (void*)&beta1,
    (void*)&w2, (void*)&b2, (void*)&gamma2, (void*)&beta2,
    (void*)&gw1, (void*)&gb1, (void*)&gw2, (void*)&gb2, (void*)&gw3, (void*)&gb3,
    (void*)&ew1, (void*)&eb1, (void*)&ew2, (void*)&eb2, (void*)&ew3, (void*)&eb3,
    (void*)&wsf, (void*)&outp
  };
  hipLaunchCooperativeKernel(reinterpret_cast<void*>(fused), dim3(128), dim3(512),
                             args, 0, stream);
}

// Round 6
// 278.787 us; speedup vs baseline: 1.0383x; 1.0383x over previous
//
#include <hip/hip_runtime.h>
#include <math.h>

// Network_22892175688023 — round 6: R5 structure with the k_gen3 eb3L fill bug fixed
// (was `if (t<512)` from the 512-thread R4 kernel; with 256 threads experts 4-7 got
// uninitialized LDS -> 5e30). Also: explicit 16B alignment on LDS ushort arrays
// accessed via b128 vector casts.
//
//   A k_prep_enc1 : weight->fragment planes (blocks 0-447) + enc L1 + stat slots (448-703)
//   B k_enc2      : reduce slots1, bn1+relu, enc L2, slots2       (64 blocks x 16 rows)
//   D k_gate_gen1 : reduce slots2, bn2, gating->bc, MFMA gen L1 -> act planes
//   E k_gen2      : MFMA gen L2 -> act planes
//   F k_gen3      : MFMA gen L3 + bias -> out

#define DIN 103
#define NE  8
#define HH  256
#define DOUT 51
#define EPSBN 1e-5f

typedef __attribute__((ext_vector_type(8))) short bf16x8;
typedef __attribute__((ext_vector_type(4))) float f32x4;
typedef __attribute__((ext_vector_type(8))) unsigned short us8;

__device__ __forceinline__ float eluf(float v) { return v > 0.f ? v : (expf(v) - 1.f); }
__device__ __forceinline__ unsigned short bf16h(float f) {
  unsigned u = __float_as_uint(f);
  u += 0x7FFFu + ((u >> 16) & 1u);
  return (unsigned short)(u >> 16);
}
__device__ __forceinline__ float bf16f(unsigned short h) { return __uint_as_float(((unsigned)h) << 16); }
__device__ __forceinline__ void split_bf16(float v, unsigned short& h, unsigned short& l) {
  h = bf16h(v);
  l = bf16h(v - bf16f(h));
}
#define MFMA __builtin_amdgcn_mfma_f32_16x16x32_bf16

// ---- ws layout (float offsets) ----
// slots1@0(32768) slots2@32768(4096) bcg@36864(8192) h1raw@45056(65536) h2raw@110592(32768)
// E1H@143360 E1L@274432 | E2H@405504 E2L@667648 | E3H@929792 E3L@995328
// A1H@1060864 A1L@1191936 | A2H@1323008 A2L@1454080

// ================= A: prep planes + enc layer 1 =================
__global__ __launch_bounds__(256) void k_prep_enc1(
    const float* __restrict__ x, const float* __restrict__ w1, const float* __restrict__ b1,
    const float* __restrict__ ew1, const float* __restrict__ ew2, const float* __restrict__ ew3,
    float* __restrict__ ws) {
  int bk = blockIdx.x, t = threadIdx.x;
  if (bk < 448) {                       // ---- prep: 448*256 = 114688 threads exactly
    unsigned short* E1H = (unsigned short*)(ws + 143360);
    unsigned short* E1L = (unsigned short*)(ws + 274432);
    unsigned short* E2H = (unsigned short*)(ws + 405504);
    unsigned short* E2L = (unsigned short*)(ws + 667648);
    unsigned short* E3H = (unsigned short*)(ws + 929792);
    unsigned short* E3L = (unsigned short*)(ws + 995328);
    int G = bk * 256 + t;
    int g = G >> 6, ll = G & 63;
    int c = ll & 15, q = ll >> 4;
    us8 H8, L8;
    if (g < 512) {                       // E1: g = (e*16+ns)*4+kc
      int kc = g & 3, ns = (g >> 2) & 15, e = g >> 6;
      int n = ns * 16 + c, k0 = kc * 32 + q * 8;
#pragma unroll
      for (int j = 0; j < 8; ++j) {
        int k = k0 + j;
        float v = (k < DIN) ? ew1[((size_t)e * DIN + k) * HH + n] : 0.f;
        unsigned short h, lo; split_bf16(v, h, lo); H8[j] = h; L8[j] = lo;
      }
      *(us8*)(E1H + (size_t)g * 512 + ll * 8) = H8;
      *(us8*)(E1L + (size_t)g * 512 + ll * 8) = L8;
    } else if (g < 1536) {               // E2: g2 = (e*16+ns)*8+kc
      int g2 = g - 512;
      int kc = g2 & 7, ns = (g2 >> 3) & 15, e = g2 >> 7;
      int n = ns * 16 + c, k0 = kc * 32 + q * 8;
#pragma unroll
      for (int j = 0; j < 8; ++j) {
        float v = ew2[((size_t)e * HH + k0 + j) * HH + n];
        unsigned short h, lo; split_bf16(v, h, lo); H8[j] = h; L8[j] = lo;
      }
      *(us8*)(E2H + (size_t)g2 * 512 + ll * 8) = H8;
      *(us8*)(E2L + (size_t)g2 * 512 + ll * 8) = L8;
    } else {                             // E3: g3 = (e*4+ns)*8+kc, N pad 51->64
      int g3 = g - 1536;
      int kc = g3 & 7, ns = (g3 >> 3) & 3, e = g3 >> 5;
      int n = ns * 16 + c, k0 = kc * 32 + q * 8;
#pragma unroll
      for (int j = 0; j < 8; ++j) {
        float v = (n < DOUT) ? ew3[((size_t)e * HH + k0 + j) * DOUT + n] : 0.f;
        unsigned short h, lo; split_bf16(v, h, lo); H8[j] = h; L8[j] = lo;
      }
      *(us8*)(E3H + (size_t)g3 * 512 + ll * 8) = H8;
      *(us8*)(E3L + (size_t)g3 * 512 + ll * 8) = L8;
    }
  } else {                              // ---- enc layer 1: 4 rows/block
    __shared__ float w1L[64 * DIN];
    __shared__ float xr[4][104];
    __shared__ float hb[4][64];
    float* slots1 = ws;
    float* h1raw  = ws + 45056;
    int bkl = bk - 448;
    int r0 = bkl * 4;
    for (int i = t; i < 64 * DIN; i += 256) w1L[i] = w1[i];
    for (int i = t; i < 416; i += 256) {
      int r = i / 104, c2 = i - r * 104;
      float v = 0.f;
      if (c2 < DIN) { v = x[(size_t)(r0 + r) * DIN + c2]; if (c2 >= 100) v *= 100.f; }
      xr[r][c2] = v;
    }
    __syncthreads();
    {
      int r = t >> 6, j = t & 63;
      float acc = b1[j];
      for (int i = 0; i < DIN; ++i) acc = fmaf(xr[r][i], w1L[j * DIN + i], acc);
      hb[r][j] = acc;
      h1raw[(size_t)(r0 + r) * 64 + j] = acc;
    }
    __syncthreads();
    if (t < 64) {
      float s = 0.f, q = 0.f;
      for (int r = 0; r < 4; ++r) { float v = hb[r][t]; s += v; q += v * v; }
      slots1[bkl * 128 + t] = s;
      slots1[bkl * 128 + 64 + t] = q;
    }
  }
}

// ================= B: bn1+relu, enc layer 2 =================
__global__ __launch_bounds__(256) void k_enc2(
    const float* __restrict__ gamma1, const float* __restrict__ beta1,
    const float* __restrict__ w2, const float* __restrict__ b2, float* __restrict__ ws) {
  __shared__ float w2T[64 * 33];
  __shared__ float red2[256], red[128];
  __shared__ float sc1[64], sh1[64];
  __shared__ float h1b[16][64];
  __shared__ float hb2[16][32];
  float* slots1 = ws;
  float* slots2 = ws + 32768;
  float* h1raw  = ws + 45056;
  float* h2raw  = ws + 110592;
  int bk = blockIdx.x, t = threadIdx.x;
  int R0 = bk * 16;
  for (int i = t; i < 2048; i += 256) { int j = i >> 6, k = i & 63; w2T[k * 33 + j] = w2[i]; }
  {
    int col = t & 127, half = t >> 7;
    float s = 0.f;
    for (int b = half * 128; b < half * 128 + 128; ++b) s += slots1[b * 128 + col];
    red2[t] = s;
  }
  __syncthreads();
  if (t < 128) red[t] = red2[t] + red2[128 + t];
  __syncthreads();
  if (t < 64) {
    float m = red[t] * (1.f / 1024.f);
    float v = red[64 + t] * (1.f / 1024.f) - m * m;
    float sc = gamma1[t] * rsqrtf(v + EPSBN);
    sc1[t] = sc; sh1[t] = beta1[t] - m * sc;
  }
  __syncthreads();
#pragma unroll
  for (int i = 0; i < 4; ++i) {
    int idx = t + i * 256;
    int r = idx >> 6, k = idx & 63;
    h1b[r][k] = fmaxf(fmaf(h1raw[(size_t)(R0 + r) * 64 + k], sc1[k], sh1[k]), 0.f);
  }
  __syncthreads();
#pragma unroll
  for (int i = 0; i < 2; ++i) {
    int o = t + i * 256;
    int r = o >> 5, j = o & 31;
    float acc = b2[j];
    for (int k = 0; k < 64; ++k) acc = fmaf(h1b[r][k], w2T[k * 33 + j], acc);
    hb2[r][j] = acc;
    h2raw[(size_t)(R0 + r) * 32 + j] = acc;
  }
  __syncthreads();
  if (t < 32) {
    float s = 0.f, q = 0.f;
    for (int r = 0; r < 16; ++r) { float v = hb2[r][t]; s += v; q += v * v; }
    slots2[bk * 64 + t] = s;
    slots2[bk * 64 + 32 + t] = q;
  }
}

// ================= D: bn2 + gating -> bc, MFMA gen layer 1 =================
__global__ __launch_bounds__(256) void k_gate_gen1(
    const float* __restrict__ x,
    const float* __restrict__ gamma2, const float* __restrict__ beta2,
    const float* __restrict__ gw1, const float* __restrict__ gb1,
    const float* __restrict__ gw2, const float* __restrict__ gb2,
    const float* __restrict__ gw3, const float* __restrict__ gb3,
    const float* __restrict__ eb1, float* __restrict__ ws) {
  __shared__ float red2[64], sc2[32], sh2[32];
  __shared__ float lat[16][32];
  __shared__ float gw1L[64 * 33], gw2L[64 * 65], gw3L[8 * 65];
  __shared__ float gb1L[64], gb2L[64], gb3L[8];
  __shared__ float g1[16][64], g2[16][64];
  __shared__ float bcL[16][8];
  __shared__ float eb1L[8][256];
  __shared__ __attribute__((aligned(16))) unsigned short xfH[2048], xfL[2048];
  __shared__ __attribute__((aligned(16))) unsigned short a1Hs[4096], a1Ls[4096];
  float* slots2 = ws + 32768;
  float* bcg    = ws + 36864;
  float* h2raw  = ws + 110592;
  const unsigned short* E1H = (const unsigned short*)(ws + 143360);
  const unsigned short* E1L = (const unsigned short*)(ws + 274432);
  unsigned short* A1H = (unsigned short*)(ws + 1060864);
  unsigned short* A1L = (unsigned short*)(ws + 1191936);
  int bk = blockIdx.x, t = threadIdx.x;
  int wv = t >> 6, l = t & 63;
  int c = l & 15, quad = l >> 4;
  int R0 = bk * 16;

  for (int i = t; i < 2048; i += 256) { int j = i >> 5, k = i & 31; gw1L[j * 33 + k] = gw1[i]; }
  for (int i = t; i < 4096; i += 256) { int j = i >> 6, k = i & 63; gw2L[j * 65 + k] = gw2[i]; }
  for (int i = t; i < 512; i += 256) { int j = i >> 6, k = i & 63; gw3L[j * 65 + k] = gw3[i]; }
  for (int i = t; i < 2048; i += 256) ((float*)eb1L)[i] = eb1[i];
  if (t < 64) { gb1L[t] = gb1[t]; gb2L[t] = gb2[t]; }
  if (t < 8) gb3L[t] = gb3[t];
  if (t < 64) {
    float s = 0.f;
    for (int b = 0; b < 64; ++b) s += slots2[b * 64 + t];
    red2[t] = s;
  }
  for (int tau = t; tau < 2048; tau += 256) {   // x fragments for 16 rows
    int kc = tau >> 9, rem = tau & 511;
    int lp = rem >> 3, j = rem & 7;
    int bl = lp & 15, qq = lp >> 4;
    int k = kc * 32 + qq * 8 + j;
    float v = 0.f;
    if (k < DIN) { v = x[(size_t)(R0 + bl) * DIN + k]; if (k >= 100) v *= 100.f; }
    unsigned short h, lo; split_bf16(v, h, lo);
    xfH[tau] = h; xfL[tau] = lo;
  }
  __syncthreads();
  if (t < 32) {
    float m = red2[t] * (1.f / 1024.f);
    float v = red2[32 + t] * (1.f / 1024.f) - m * m;
    float sc = gamma2[t] * rsqrtf(v + EPSBN);
    sc2[t] = sc; sh2[t] = beta2[t] - m * sc;
  }
  __syncthreads();
#pragma unroll
  for (int i = 0; i < 2; ++i) {
    int idx = t + i * 256;
    int r = idx >> 5, cc = idx & 31;
    lat[r][cc] = fmaxf(fmaf(h2raw[(size_t)(R0 + r) * 32 + cc], sc2[cc], sh2[cc]), 0.f);
  }
  __syncthreads();
#pragma unroll
  for (int rr = 0; rr < 4; ++rr) {
    int r = wv * 4 + rr;
    float a1 = gb1L[l];
    for (int k = 0; k < 32; ++k) a1 = fmaf(gw1L[l * 33 + k], lat[r][k], a1);
    g1[r][l] = eluf(a1);
  }
  __syncthreads();
#pragma unroll
  for (int rr = 0; rr < 4; ++rr) {
    int r = wv * 4 + rr;
    float a2 = gb2L[l];
    for (int k = 0; k < 64; ++k) a2 = fmaf(gw2L[l * 65 + k], g1[r][k], a2);
    g2[r][l] = eluf(a2);
  }
  __syncthreads();
#pragma unroll
  for (int rr = 0; rr < 4; ++rr) {
    int r = wv * 4 + rr;
    if (l < 8) {
      float a3 = gb3L[l];
      for (int k = 0; k < 64; ++k) a3 = fmaf(gw3L[l * 65 + k], g2[r][k], a3);
      float mx = a3;
      mx = fmaxf(mx, __shfl_xor(mx, 1));
      mx = fmaxf(mx, __shfl_xor(mx, 2));
      mx = fmaxf(mx, __shfl_xor(mx, 4));
      float p = expf(a3 - mx);
      float sp = p;
      sp += __shfl_xor(sp, 1); sp += __shfl_xor(sp, 2); sp += __shfl_xor(sp, 4);
      float b = p / sp;
      bcL[r][l] = b;
      bcg[(size_t)(R0 + r) * 8 + l] = b;
    }
  }
  __syncthreads();

  // ---- gen layer 1: h1 = elu(sum_e bc*(xs@ew1_e) + sum_e bc*eb1_e) ----
  bf16x8 xh[4], xl[4];
#pragma unroll
  for (int kc = 0; kc < 4; ++kc) {
    xh[kc] = *(const bf16x8*)(xfH + kc * 512 + l * 8);
    xl[kc] = *(const bf16x8*)(xfL + kc * 512 + l * 8);
  }
  for (int nsi = 0; nsi < 4; ++nsi) {
    int ns = wv * 4 + nsi;
    f32x4 tot = {0.f, 0.f, 0.f, 0.f};
    for (int e = 0; e < NE; ++e) {
      f32x4 acc = {0.f, 0.f, 0.f, 0.f};
#pragma unroll
      for (int kc = 0; kc < 4; ++kc) {
        size_t bo = ((size_t)((e * 16 + ns) * 4 + kc)) * 512 + l * 8;
        bf16x8 bh = *(const bf16x8*)(E1H + bo);
        bf16x8 bl2 = *(const bf16x8*)(E1L + bo);
        acc = MFMA(xh[kc], bh, acc, 0, 0, 0);
        acc = MFMA(xl[kc], bh, acc, 0, 0, 0);
        acc = MFMA(xh[kc], bl2, acc, 0, 0, 0);
      }
#pragma unroll
      for (int r = 0; r < 4; ++r) tot[r] = fmaf(bcL[quad * 4 + r][e], acc[r], tot[r]);
    }
    int col = ns * 16 + c;
#pragma unroll
    for (int r = 0; r < 4; ++r) {
      float bb = 0.f;
#pragma unroll
      for (int e = 0; e < NE; ++e) bb = fmaf(bcL[quad * 4 + r][e], eb1L[e][col], bb);
      float v = eluf(tot[r] + bb);
      unsigned short h, lo; split_bf16(v, h, lo);
      int dst = (ns >> 1) * 512 + (((ns & 1) * 2 + (c >> 3)) * 16 + quad * 4 + r) * 8 + (c & 7);
      a1Hs[dst] = h; a1Ls[dst] = lo;
    }
  }
  __syncthreads();
  for (int i = t; i < 512; i += 256) {
    *(us8*)(A1H + (size_t)bk * 4096 + i * 8) = *(const us8*)(a1Hs + i * 8);
    *(us8*)(A1L + (size_t)bk * 4096 + i * 8) = *(const us8*)(a1Ls + i * 8);
  }
}

// ================= E: MFMA gen layer 2 =================
__global__ __launch_bounds__(256) void k_gen2(const float* __restrict__ eb2, float* __restrict__ ws) {
  __shared__ float eb2L[8][256];
  __shared__ float bcL[16][8];
  __shared__ __attribute__((aligned(16))) unsigned short a2Hs[4096], a2Ls[4096];
  float* bcg = ws + 36864;
  const unsigned short* E2H = (const unsigned short*)(ws + 405504);
  const unsigned short* E2L = (const unsigned short*)(ws + 667648);
  const unsigned short* A1H = (const unsigned short*)(ws + 1060864);
  const unsigned short* A1L = (const unsigned short*)(ws + 1191936);
  unsigned short* A2H = (unsigned short*)(ws + 1323008);
  unsigned short* A2L = (unsigned short*)(ws + 1454080);
  int bk = blockIdx.x, t = threadIdx.x;
  int wv = t >> 6, l = t & 63;
  int c = l & 15, quad = l >> 4;
  int R0 = bk * 16;
  for (int i = t; i < 2048; i += 256) ((float*)eb2L)[i] = eb2[i];
  if (t < 128) bcL[t >> 3][t & 7] = bcg[(size_t)(R0 + (t >> 3)) * 8 + (t & 7)];
  __syncthreads();
  bf16x8 ah[8], al[8];
#pragma unroll
  for (int kc = 0; kc < 8; ++kc) {
    ah[kc] = *(const bf16x8*)(A1H + (size_t)bk * 4096 + kc * 512 + l * 8);
    al[kc] = *(const bf16x8*)(A1L + (size_t)bk * 4096 + kc * 512 + l * 8);
  }
  for (int nsi = 0; nsi < 4; ++nsi) {
    int ns = wv * 4 + nsi;
    f32x4 tot = {0.f, 0.f, 0.f, 0.f};
    for (int e = 0; e < NE; ++e) {
      f32x4 acc = {0.f, 0.f, 0.f, 0.f};
#pragma unroll
      for (int kc = 0; kc < 8; ++kc) {
        size_t bo = ((size_t)((e * 16 + ns) * 8 + kc)) * 512 + l * 8;
        bf16x8 bh = *(const bf16x8*)(E2H + bo);
        bf16x8 bl2 = *(const bf16x8*)(E2L + bo);
        acc = MFMA(ah[kc], bh, acc, 0, 0, 0);
        acc = MFMA(al[kc], bh, acc, 0, 0, 0);
        acc = MFMA(ah[kc], bl2, acc, 0, 0, 0);
      }
#pragma unroll
      for (int r = 0; r < 4; ++r) tot[r] = fmaf(bcL[quad * 4 + r][e], acc[r], tot[r]);
    }
    int col = ns * 16 + c;
#pragma unroll
    for (int r = 0; r < 4; ++r) {
      float bb = 0.f;
#pragma unroll
      for (int e = 0; e < NE; ++e) bb = fmaf(bcL[quad * 4 + r][e], eb2L[e][col], bb);
      float v = eluf(tot[r] + bb);
      unsigned short h, lo; split_bf16(v, h, lo);
      int dst = (ns >> 1) * 512 + (((ns & 1) * 2 + (c >> 3)) * 16 + quad * 4 + r) * 8 + (c & 7);
      a2Hs[dst] = h; a2Ls[dst] = lo;
    }
  }
  __syncthreads();
  for (int i = t; i < 512; i += 256) {
    *(us8*)(A2H + (size_t)bk * 4096 + i * 8) = *(const us8*)(a2Hs + i * 8);
    *(us8*)(A2L + (size_t)bk * 4096 + i * 8) = *(const us8*)(a2Ls + i * 8);
  }
}

// ================= F: MFMA gen layer 3 + out =================
__global__ __launch_bounds__(256) void k_gen3(const float* __restrict__ eb3,
    float* __restrict__ ws, float* __restrict__ out) {
  __shared__ float eb3L[8][64];
  __shared__ float bcL[16][8];
  float* bcg = ws + 36864;
  const unsigned short* E3H = (const unsigned short*)(ws + 929792);
  const unsigned short* E3L = (const unsigned short*)(ws + 995328);
  const unsigned short* A2H = (const unsigned short*)(ws + 1323008);
  const unsigned short* A2L = (const unsigned short*)(ws + 1454080);
  int bk = blockIdx.x, t = threadIdx.x;
  int wv = t >> 6, l = t & 63;
  int c = l & 15, quad = l >> 4;
  int R0 = bk * 16;
  for (int i = t; i < 512; i += 256) {            // FIX: was `if (t < 512)` (512-thread R4 relic)
    int e = i >> 6, n = i & 63;
    eb3L[e][n] = (n < DOUT) ? eb3[e * DOUT + n] : 0.f;
  }
  if (t < 128) bcL[t >> 3][t & 7] = bcg[(size_t)(R0 + (t >> 3)) * 8 + (t & 7)];
  __syncthreads();
  bf16x8 ah[8], al[8];
#pragma unroll
  for (int kc = 0; kc < 8; ++kc) {
    ah[kc] = *(const bf16x8*)(A2H + (size_t)bk * 4096 + kc * 512 + l * 8);
    al[kc] = *(const bf16x8*)(A2L + (size_t)bk * 4096 + kc * 512 + l * 8);
  }
  int ns = wv;                    // 4 waves x 16 cols = 64 (51 padded)
  f32x4 tot = {0.f, 0.f, 0.f, 0.f};
  for (int e = 0; e < NE; ++e) {
    f32x4 acc = {0.f, 0.f, 0.f, 0.f};
#pragma unroll
    for (int kc = 0; kc < 8; ++kc) {
      size_t bo = ((size_t)((e * 4 + ns) * 8 + kc)) * 512 + l * 8;
      bf16x8 bh = *(const bf16x8*)(E3H + bo);
      bf16x8 bl2 = *(const bf16x8*)(E3L + bo);
      acc = MFMA(ah[kc], bh, acc, 0, 0, 0);
      acc = MFMA(al[kc], bh, acc, 0, 0, 0);
      acc = MFMA(ah[kc], bl2, acc, 0, 0, 0);
    }
#pragma unroll
    for (int r = 0; r < 4; ++r) tot[r] = fmaf(bcL[quad * 4 + r][e], acc[r], tot[r]);
  }
  int col = ns * 16 + c;
#pragma unroll
  for (int r = 0; r < 4; ++r) {
    float bb = 0.f;
#pragma unroll
    for (int e = 0; e < NE; ++e) bb = fmaf(bcL[quad * 4 + r][e], eb3L[e][col], bb);
    float v = tot[r] + bb;
    if (col < DOUT) out[(size_t)(R0 + quad * 4 + r) * DOUT + col] = v;
  }
}

extern "C" void kernel_launch(void* const* d_in, const int* in_sizes, int n_in,
                              void* d_out, int out_size, void* d_ws, size_t ws_size,
                              hipStream_t stream) {
  const float* x      = (const float*)d_in[0];
  const float* w1     = (const float*)d_in[1];
  const float* b1     = (const float*)d_in[2];
  const float* gamma1 = (const float*)d_in[3];
  const float* beta1  = (const float*)d_in[4];
  const float* w2     = (const float*)d_in[5];
  const float* b2     = (const float*)d_in[6];
  const float* gamma2 = (const float*)d_in[7];
  const float* beta2  = (const float*)d_in[8];
  const float* gw1    = (const float*)d_in[9];
  const float* gb1    = (const float*)d_in[10];
  const float* gw2    = (const float*)d_in[11];
  const float* gb2    = (const float*)d_in[12];
  const float* gw3    = (const float*)d_in[13];
  const float* gb3    = (const float*)d_in[14];
  const float* ew1    = (const float*)d_in[15];
  const float* eb1    = (const float*)d_in[16];
  const float* ew2    = (const float*)d_in[17];
  const float* eb2    = (const float*)d_in[18];
  const float* ew3    = (const float*)d_in[19];
  const float* eb3    = (const float*)d_in[20];
  float* wsf  = (float*)d_ws;
  float* outp = (float*)d_out;

  k_prep_enc1<<<704, 256, 0, stream>>>(x, w1, b1, ew1, ew2, ew3, wsf);
  k_enc2<<<64, 256, 0, stream>>>(gamma1, beta1, w2, b2, wsf);
  k_gate_gen1<<<64, 256, 0, stream>>>(x, gamma2, beta2, gw1, gb1, gw2, gb2, gw3, gb3, eb1, wsf);
  k_gen2<<<64, 256, 0, stream>>>(eb2, wsf);
  k_gen3<<<64, 256, 0, stream>>>(eb3, wsf, outp);
}

// Round 7
// 166.693 us; speedup vs baseline: 1.7366x; 1.6725x over previous
//
#include <hip/hip_runtime.h>
#include <math.h>

// Network_22892175688023 — round 7: wide grids, verified pieces, ~1us/node launches.
//   k_prep  : all operands -> fragment-order bf16 hi/lo planes (LDS-transpose, coalesced reads)
//   k_enc1  : MFMA  h1raw = xs@w1^T + b1  + per-block stat slots      (64 blocks)
//   k_enc2  : reduce slots1, bn1+relu, enc L2 (VALU), slots2          (64 blocks)
//   k_gate  : reduce slots2, bn2, gating MLP -> bc                    (64 blocks)
//   k_gen1  : p[e] = xs @ ew1_e      (512 blocks: 64 Msub x 8 e, wave=16rx64cx1e)
//   k_comb1 : A1 = elu(sum_e bc*(p+eb1)) -> fragment planes           (128 blocks)
//   k_gen2  : p[e] = a1 @ ew2_e                                       (512 blocks)
//   k_comb2 : A2 planes                                               (128 blocks)
//   k_gen3  : p3[e] = a2 @ ew3_e                                      (128 blocks)
//   k_comb3 : out = sum_e bc*(p3+eb3)                                 (256 blocks)

#define DIN 103
#define NE  8
#define HH  256
#define DOUT 51
#define EPSBN 1e-5f

typedef __attribute__((ext_vector_type(8))) short bf16x8;
typedef __attribute__((ext_vector_type(4))) float f32x4;
typedef __attribute__((ext_vector_type(8))) unsigned short us8;
typedef unsigned short ushort_t;

__device__ __forceinline__ float eluf(float v) { return v > 0.f ? v : (expf(v) - 1.f); }
__device__ __forceinline__ unsigned short bf16h(float f) {
  unsigned u = __float_as_uint(f);
  u += 0x7FFFu + ((u >> 16) & 1u);
  return (unsigned short)(u >> 16);
}
__device__ __forceinline__ float bf16f(unsigned short h) { return __uint_as_float(((unsigned)h) << 16); }
__device__ __forceinline__ void split_bf16(float v, unsigned short& h, unsigned short& l) {
  h = bf16h(v);
  l = bf16h(v - bf16f(h));
}
#define MFMA __builtin_amdgcn_mfma_f32_16x16x32_bf16

// ---- ws layout (float offsets) ----
#define O_SLOTS1 0        // [64][128]
#define O_SLOTS2 8192     // [64][64]
#define O_BCG    12288    // [1024][8]
#define O_H1RAW  20480    // [1024][64]
#define O_H2RAW  86016    // [1024][32]
#define O_XSH    118784   // [64 msub][4 kc][512] sh
#define O_XSL    184320
#define O_W1H    249856   // [4 ns][4 kc][512] sh
#define O_W1L    253952
#define O_E1H    258048   // [8 e][16 ns][4 kc][512] sh
#define O_E1L    389120
#define O_E2H    520192   // [8 e][16 ns][8 kc][512] sh
#define O_E2L    782336
#define O_E3H    1044480  // [8 e][4 ns][8 kc][512] sh
#define O_E3L    1110016
#define O_A1H    1175552  // [64 msub][8 kc][512] sh
#define O_A1L    1306624
#define O_A2H    1437696
#define O_A2L    1568768
#define O_P      1699840  // [8][1024][256] f32 (p3 reuses as [8][1024][64])

// ================= prep: coalesced reads -> LDS tile -> fragment planes =================
// blocks: E2 0..255 (e*32 + kc*4 + nh) | E1 256..383 (e*16 + kc*4 + nh)
//         E3 384..447 (e*8 + kc) | W1 448..451 (kc) | Xs 452..515 (msub)
__global__ __launch_bounds__(256) void k_prep(
    const float* __restrict__ x, const float* __restrict__ w1,
    const float* __restrict__ ew1, const float* __restrict__ ew2, const float* __restrict__ ew3,
    float* __restrict__ ws) {
  __shared__ float tile[32][65];
  int bk = blockIdx.x, t = threadIdx.x;
  int l2 = t & 63, c = l2 & 15, q = l2 >> 4;

  if (bk < 256) {          // ---- E2: K=256, N=256 ----
    int nh = bk & 3, kc = (bk >> 2) & 7, e = bk >> 5;
    int k0 = kc * 32, n0 = nh * 64;
#pragma unroll
    for (int i = 0; i < 8; ++i) {
      int kl = (t >> 6) + i * 4;
      tile[kl][t & 63] = ew2[((size_t)e * HH + k0 + kl) * HH + n0 + (t & 63)];
    }
    __syncthreads();
    int nsl = t >> 6;
    us8 H8, L8;
#pragma unroll
    for (int j = 0; j < 8; ++j) {
      unsigned short h, lo; split_bf16(tile[q * 8 + j][nsl * 16 + c], h, lo);
      H8[j] = h; L8[j] = lo;
    }
    size_t dst = (((size_t)(e * 16 + nh * 4 + nsl)) * 8 + kc) * 512 + l2 * 8;
    *(us8*)((ushort_t*)(ws + O_E2H) + dst) = H8;
    *(us8*)((ushort_t*)(ws + O_E2L) + dst) = L8;
  } else if (bk < 384) {   // ---- E1: K=103->128, N=256 ----
    int b2 = bk - 256;
    int nh = b2 & 3, kc = (b2 >> 2) & 3, e = b2 >> 4;
    int k0 = kc * 32, n0 = nh * 64;
#pragma unroll
    for (int i = 0; i < 8; ++i) {
      int kl = (t >> 6) + i * 4;
      int k = k0 + kl;
      tile[kl][t & 63] = (k < DIN) ? ew1[((size_t)e * DIN + k) * HH + n0 + (t & 63)] : 0.f;
    }
    __syncthreads();
    int nsl = t >> 6;
    us8 H8, L8;
#pragma unroll
    for (int j = 0; j < 8; ++j) {
      unsigned short h, lo; split_bf16(tile[q * 8 + j][nsl * 16 + c], h, lo);
      H8[j] = h; L8[j] = lo;
    }
    size_t dst = (((size_t)(e * 16 + nh * 4 + nsl)) * 4 + kc) * 512 + l2 * 8;
    *(us8*)((ushort_t*)(ws + O_E1H) + dst) = H8;
    *(us8*)((ushort_t*)(ws + O_E1L) + dst) = L8;
  } else if (bk < 448) {   // ---- E3: K=256, N=51->64 ----
    int b2 = bk - 384;
    int kc = b2 & 7, e = b2 >> 3;
    int k0 = kc * 32;
#pragma unroll
    for (int i = 0; i < 8; ++i) {
      int kl = (t >> 6) + i * 4;
      int n = t & 63;
      tile[kl][n] = (n < DOUT) ? ew3[((size_t)e * HH + k0 + kl) * DOUT + n] : 0.f;
    }
    __syncthreads();
    int nsl = t >> 6;
    us8 H8, L8;
#pragma unroll
    for (int j = 0; j < 8; ++j) {
      unsigned short h, lo; split_bf16(tile[q * 8 + j][nsl * 16 + c], h, lo);
      H8[j] = h; L8[j] = lo;
    }
    size_t dst = (((size_t)(e * 4 + nsl)) * 8 + kc) * 512 + l2 * 8;
    *(us8*)((ushort_t*)(ws + O_E3H) + dst) = H8;
    *(us8*)((ushort_t*)(ws + O_E3L) + dst) = L8;
  } else if (bk < 452) {   // ---- W1: B[k][n=j] from w1[j][k], K=103->128, N=64 ----
    int kc = bk - 448;
    int k0 = kc * 32;
    // stage transposed: tile[n=j up to 64? -> use [32k][65] as [j][k]] need [64][33]:
    __shared__ float tw[64][33];
#pragma unroll
    for (int p8 = 0; p8 < 8; ++p8) {
      int j = (t >> 5) + p8 * 8;
      int kl = t & 31;
      int k = k0 + kl;
      tw[j][kl] = (k < DIN) ? w1[(size_t)j * DIN + k] : 0.f;
    }
    __syncthreads();
    int nsl = t >> 6;
    us8 H8, L8;
#pragma unroll
    for (int j = 0; j < 8; ++j) {
      unsigned short h, lo; split_bf16(tw[nsl * 16 + c][q * 8 + j], h, lo);
      H8[j] = h; L8[j] = lo;
    }
    size_t dst = ((size_t)nsl * 4 + kc) * 512 + l2 * 8;
    *(us8*)((ushort_t*)(ws + O_W1H) + dst) = H8;
    *(us8*)((ushort_t*)(ws + O_W1L) + dst) = L8;
  } else {                 // ---- Xs: A-fragments of scaled x, 16 rows/block, K=103->128 ----
    int msub = bk - 452;
    __shared__ float xt[16][104];
    for (int i = t; i < 16 * 104; i += 256) {
      int b = i / 104, k = i - b * 104;
      float v = 0.f;
      if (k < DIN) { v = x[(size_t)(msub * 16 + b) * DIN + k]; if (k >= 100) v *= 100.f; }
      xt[b][k] = v;
    }
    __syncthreads();
    int kc = t >> 6;
    int m = c;
    us8 H8, L8;
#pragma unroll
    for (int j = 0; j < 8; ++j) {
      int k = kc * 32 + q * 8 + j;
      float v = (k < 104) ? xt[m][k] : 0.f;
      unsigned short h, lo; split_bf16(v, h, lo);
      H8[j] = h; L8[j] = lo;
    }
    size_t dst = ((size_t)msub * 4 + kc) * 512 + l2 * 8;
    *(us8*)((ushort_t*)(ws + O_XSH) + dst) = H8;
    *(us8*)((ushort_t*)(ws + O_XSL) + dst) = L8;
  }
}

// ================= enc1: MFMA h1raw = xs@w1^T + b1, stat slots =================
__global__ __launch_bounds__(256) void k_enc1(const float* __restrict__ b1, float* __restrict__ ws) {
  __shared__ float tile[16][65];
  int bk = blockIdx.x, t = threadIdx.x;
  int wv = t >> 6, l = t & 63, c = l & 15, quad = l >> 4;
  const ushort_t* XsH = (const ushort_t*)(ws + O_XSH);
  const ushort_t* XsL = (const ushort_t*)(ws + O_XSL);
  const ushort_t* W1H = (const ushort_t*)(ws + O_W1H);
  const ushort_t* W1L = (const ushort_t*)(ws + O_W1L);
  float* h1raw  = ws + O_H1RAW;
  float* slots1 = ws + O_SLOTS1;
  f32x4 acc = {0.f, 0.f, 0.f, 0.f};
#pragma unroll
  for (int kc = 0; kc < 4; ++kc) {
    bf16x8 ah = *(const bf16x8*)(XsH + ((size_t)bk * 4 + kc) * 512 + l * 8);
    bf16x8 al = *(const bf16x8*)(XsL + ((size_t)bk * 4 + kc) * 512 + l * 8);
    bf16x8 bh = *(const bf16x8*)(W1H + ((size_t)wv * 4 + kc) * 512 + l * 8);
    bf16x8 bl = *(const bf16x8*)(W1L + ((size_t)wv * 4 + kc) * 512 + l * 8);
    acc = MFMA(ah, bh, acc, 0, 0, 0);
    acc = MFMA(al, bh, acc, 0, 0, 0);
    acc = MFMA(ah, bl, acc, 0, 0, 0);
  }
  int col = wv * 16 + c;
  float b1v = b1[col];
#pragma unroll
  for (int r = 0; r < 4; ++r) {
    float v = acc[r] + b1v;
    tile[quad * 4 + r][col] = v;
    h1raw[(size_t)(bk * 16 + quad * 4 + r) * 64 + col] = v;
  }
  __syncthreads();
  if (t < 64) {
    float s = 0.f, qq = 0.f;
    for (int r = 0; r < 16; ++r) { float v = tile[r][t]; s += v; qq += v * v; }
    slots1[bk * 128 + t] = s;
    slots1[bk * 128 + 64 + t] = qq;
  }
}

// ================= enc2: reduce stats1, bn1+relu, enc L2 (VALU), slots2 =================
__global__ __launch_bounds__(256) void k_enc2(
    const float* __restrict__ gamma1, const float* __restrict__ beta1,
    const float* __restrict__ w2, const float* __restrict__ b2, float* __restrict__ ws) {
  __shared__ float w2T[64 * 33];
  __shared__ float red[128];
  __shared__ float sc1[64], sh1[64];
  __shared__ float h1b[16][64];
  __shared__ float hb2[16][32];
  float* slots1 = ws + O_SLOTS1;
  float* slots2 = ws + O_SLOTS2;
  float* h1raw  = ws + O_H1RAW;
  float* h2raw  = ws + O_H2RAW;
  int bk = blockIdx.x, t = threadIdx.x;
  int R0 = bk * 16;
  for (int i = t; i < 2048; i += 256) { int j = i >> 6, k = i & 63; w2T[k * 33 + j] = w2[i]; }
  if (t < 128) {
    float s = 0.f;
    for (int b = 0; b < 64; ++b) s += slots1[b * 128 + t];
    red[t] = s;
  }
  __syncthreads();
  if (t < 64) {
    float m = red[t] * (1.f / 1024.f);
    float v = red[64 + t] * (1.f / 1024.f) - m * m;
    float sc = gamma1[t] * rsqrtf(v + EPSBN);
    sc1[t] = sc; sh1[t] = beta1[t] - m * sc;
  }
  __syncthreads();
#pragma unroll
  for (int i = 0; i < 4; ++i) {
    int idx = t + i * 256;
    int r = idx >> 6, k = idx & 63;
    h1b[r][k] = fmaxf(fmaf(h1raw[(size_t)(R0 + r) * 64 + k], sc1[k], sh1[k]), 0.f);
  }
  __syncthreads();
#pragma unroll
  for (int i = 0; i < 2; ++i) {
    int o = t + i * 256;
    int r = o >> 5, j = o & 31;
    float acc = b2[j];
    for (int k = 0; k < 64; ++k) acc = fmaf(h1b[r][k], w2T[k * 33 + j], acc);
    hb2[r][j] = acc;
    h2raw[(size_t)(R0 + r) * 32 + j] = acc;
  }
  __syncthreads();
  if (t < 32) {
    float s = 0.f, q = 0.f;
    for (int r = 0; r < 16; ++r) { float v = hb2[r][t]; s += v; q += v * v; }
    slots2[bk * 64 + t] = s;
    slots2[bk * 64 + 32 + t] = q;
  }
}

// ================= gate: reduce stats2, bn2, gating MLP -> bc =================
__global__ __launch_bounds__(256) void k_gate(
    const float* __restrict__ gamma2, const float* __restrict__ beta2,
    const float* __restrict__ gw1, const float* __restrict__ gb1,
    const float* __restrict__ gw2, const float* __restrict__ gb2,
    const float* __restrict__ gw3, const float* __restrict__ gb3,
    float* __restrict__ ws) {
  __shared__ float red2[64], sc2[32], sh2[32];
  __shared__ float lat[16][32];
  __shared__ float gw1L[64 * 33], gw2L[64 * 65], gw3L[8 * 65];
  __shared__ float gb1L[64], gb2L[64], gb3L[8];
  __shared__ float g1[16][64], g2[16][64];
  float* slots2 = ws + O_SLOTS2;
  float* bcg    = ws + O_BCG;
  float* h2raw  = ws + O_H2RAW;
  int bk = blockIdx.x, t = threadIdx.x;
  int wv = t >> 6, l = t & 63;
  int R0 = bk * 16;
  for (int i = t; i < 2048; i += 256) { int j = i >> 5, k = i & 31; gw1L[j * 33 + k] = gw1[i]; }
  for (int i = t; i < 4096; i += 256) { int j = i >> 6, k = i & 63; gw2L[j * 65 + k] = gw2[i]; }
  for (int i = t; i < 512; i += 256) { int j = i >> 6, k = i & 63; gw3L[j * 65 + k] = gw3[i]; }
  if (t < 64) { gb1L[t] = gb1[t]; gb2L[t] = gb2[t]; }
  if (t < 8) gb3L[t] = gb3[t];
  if (t < 64) {
    float s = 0.f;
    for (int b = 0; b < 64; ++b) s += slots2[b * 64 + t];
    red2[t] = s;
  }
  __syncthreads();
  if (t < 32) {
    float m = red2[t] * (1.f / 1024.f);
    float v = red2[32 + t] * (1.f / 1024.f) - m * m;
    float sc = gamma2[t] * rsqrtf(v + EPSBN);
    sc2[t] = sc; sh2[t] = beta2[t] - m * sc;
  }
  __syncthreads();
#pragma unroll
  for (int i = 0; i < 2; ++i) {
    int idx = t + i * 256;
    int r = idx >> 5, cc = idx & 31;
    lat[r][cc] = fmaxf(fmaf(h2raw[(size_t)(R0 + r) * 32 + cc], sc2[cc], sh2[cc]), 0.f);
  }
  __syncthreads();
#pragma unroll
  for (int rr = 0; rr < 4; ++rr) {
    int r = wv * 4 + rr;
    float a1 = gb1L[l];
    for (int k = 0; k < 32; ++k) a1 = fmaf(gw1L[l * 33 + k], lat[r][k], a1);
    g1[r][l] = eluf(a1);
  }
  __syncthreads();
#pragma unroll
  for (int rr = 0; rr < 4; ++rr) {
    int r = wv * 4 + rr;
    float a2 = gb2L[l];
    for (int k = 0; k < 64; ++k) a2 = fmaf(gw2L[l * 65 + k], g1[r][k], a2);
    g2[r][l] = eluf(a2);
  }
  __syncthreads();
#pragma unroll
  for (int rr = 0; rr < 4; ++rr) {
    int r = wv * 4 + rr;
    if (l < 8) {
      float a3 = gb3L[l];
      for (int k = 0; k < 64; ++k) a3 = fmaf(gw3L[l * 65 + k], g2[r][k], a3);
      float mx = a3;
      mx = fmaxf(mx, __shfl_xor(mx, 1));
      mx = fmaxf(mx, __shfl_xor(mx, 2));
      mx = fmaxf(mx, __shfl_xor(mx, 4));
      float p = expf(a3 - mx);
      float sp = p;
      sp += __shfl_xor(sp, 1); sp += __shfl_xor(sp, 2); sp += __shfl_xor(sp, 4);
      bcg[(size_t)(R0 + r) * 8 + l] = p / sp;
    }
  }
}

// ================= gen1: p[e] = xs @ ew1_e   (grid 64 x 8, wave = 16r x 64c x 1e) =================
__global__ __launch_bounds__(256) void k_gen1(float* __restrict__ ws) {
  int bk = blockIdx.x, e = blockIdx.y, t = threadIdx.x;
  int wv = t >> 6, l = t & 63, c = l & 15, quad = l >> 4;
  const ushort_t* XsH = (const ushort_t*)(ws + O_XSH);
  const ushort_t* XsL = (const ushort_t*)(ws + O_XSL);
  const ushort_t* E1H = (const ushort_t*)(ws + O_E1H);
  const ushort_t* E1L = (const ushort_t*)(ws + O_E1L);
  float* p = ws + O_P;
  f32x4 acc[4] = {};
#pragma unroll
  for (int kc = 0; kc < 4; ++kc) {
    bf16x8 ah = *(const bf16x8*)(XsH + ((size_t)bk * 4 + kc) * 512 + l * 8);
    bf16x8 al = *(const bf16x8*)(XsL + ((size_t)bk * 4 + kc) * 512 + l * 8);
#pragma unroll
    for (int nsi = 0; nsi < 4; ++nsi) {
      int ns = wv * 4 + nsi;
      size_t bo = (((size_t)(e * 16 + ns)) * 4 + kc) * 512 + l * 8;
      bf16x8 bh = *(const bf16x8*)(E1H + bo);
      bf16x8 bl = *(const bf16x8*)(E1L + bo);
      acc[nsi] = MFMA(ah, bh, acc[nsi], 0, 0, 0);
      acc[nsi] = MFMA(al, bh, acc[nsi], 0, 0, 0);
      acc[nsi] = MFMA(ah, bl, acc[nsi], 0, 0, 0);
    }
  }
  float* pe = p + (size_t)e * 262144;
#pragma unroll
  for (int nsi = 0; nsi < 4; ++nsi) {
    int col = (wv * 4 + nsi) * 16 + c;
#pragma unroll
    for (int r = 0; r < 4; ++r)
      pe[(size_t)(bk * 16 + quad * 4 + r) * 256 + col] = acc[nsi][r];
  }
}

// ================= gen2: p[e] = a1 @ ew2_e   (grid 64 x 8) =================
__global__ __launch_bounds__(256) void k_gen2(float* __restrict__ ws) {
  int bk = blockIdx.x, e = blockIdx.y, t = threadIdx.x;
  int wv = t >> 6, l = t & 63, c = l & 15, quad = l >> 4;
  const ushort_t* AH = (const ushort_t*)(ws + O_A1H);
  const ushort_t* AL = (const ushort_t*)(ws + O_A1L);
  const ushort_t* E2H = (const ushort_t*)(ws + O_E2H);
  const ushort_t* E2L = (const ushort_t*)(ws + O_E2L);
  float* p = ws + O_P;
  f32x4 acc[4] = {};
#pragma unroll
  for (int kc = 0; kc < 8; ++kc) {
    bf16x8 ah = *(const bf16x8*)(AH + ((size_t)bk * 8 + kc) * 512 + l * 8);
    bf16x8 al = *(const bf16x8*)(AL + ((size_t)bk * 8 + kc) * 512 + l * 8);
#pragma unroll
    for (int nsi = 0; nsi < 4; ++nsi) {
      int ns = wv * 4 + nsi;
      size_t bo = (((size_t)(e * 16 + ns)) * 8 + kc) * 512 + l * 8;
      bf16x8 bh = *(const bf16x8*)(E2H + bo);
      bf16x8 bl = *(const bf16x8*)(E2L + bo);
      acc[nsi] = MFMA(ah, bh, acc[nsi], 0, 0, 0);
      acc[nsi] = MFMA(al, bh, acc[nsi], 0, 0, 0);
      acc[nsi] = MFMA(ah, bl, acc[nsi], 0, 0, 0);
    }
  }
  float* pe = p + (size_t)e * 262144;
#pragma unroll
  for (int nsi = 0; nsi < 4; ++nsi) {
    int col = (wv * 4 + nsi) * 16 + c;
#pragma unroll
    for (int r = 0; r < 4; ++r)
      pe[(size_t)(bk * 16 + quad * 4 + r) * 256 + col] = acc[nsi][r];
  }
}

// ================= gen3: p3[e] = a2 @ ew3_e   (grid 64 x 2, wave = 1 expert, 64 cols) =================
__global__ __launch_bounds__(256) void k_gen3(float* __restrict__ ws) {
  int bk = blockIdx.x, eg = blockIdx.y, t = threadIdx.x;
  int wv = t >> 6, l = t & 63, c = l & 15, quad = l >> 4;
  int e = eg * 4 + wv;
  const ushort_t* AH = (const ushort_t*)(ws + O_A2H);
  const ushort_t* AL = (const ushort_t*)(ws + O_A2L);
  const ushort_t* E3H = (const ushort_t*)(ws + O_E3H);
  const ushort_t* E3L = (const ushort_t*)(ws + O_E3L);
  float* p3 = ws + O_P;
  f32x4 acc[4] = {};
#pragma unroll
  for (int kc = 0; kc < 8; ++kc) {
    bf16x8 ah = *(const bf16x8*)(AH + ((size_t)bk * 8 + kc) * 512 + l * 8);
    bf16x8 al = *(const bf16x8*)(AL + ((size_t)bk * 8 + kc) * 512 + l * 8);
#pragma unroll
    for (int nsi = 0; nsi < 4; ++nsi) {
      size_t bo = (((size_t)(e * 4 + nsi)) * 8 + kc) * 512 + l * 8;
      bf16x8 bh = *(const bf16x8*)(E3H + bo);
      bf16x8 bl = *(const bf16x8*)(E3L + bo);
      acc[nsi] = MFMA(ah, bh, acc[nsi], 0, 0, 0);
      acc[nsi] = MFMA(al, bh, acc[nsi], 0, 0, 0);
      acc[nsi] = MFMA(ah, bl, acc[nsi], 0, 0, 0);
    }
  }
  float* pe = p3 + (size_t)e * 65536;
#pragma unroll
  for (int nsi = 0; nsi < 4; ++nsi) {
    int col = nsi * 16 + c;
#pragma unroll
    for (int r = 0; r < 4; ++r)
      pe[(size_t)(bk * 16 + quad * 4 + r) * 64 + col] = acc[nsi][r];
  }
}

// ================= comb1/2: A = elu(sum_e bc*(p+eb)) -> fragment planes =================
__global__ __launch_bounds__(256) void k_comb(const float* __restrict__ eb,
    float* __restrict__ ws, int dstH, int dstL) {
  int gid = blockIdx.x * 256 + threadIdx.x;     // 32768: [64 msub][8 kc][64 l2]
  int l2 = gid & 63, kc = (gid >> 6) & 7, msub = gid >> 9;
  int b = msub * 16 + (l2 & 15);
  int k0 = kc * 32 + (l2 >> 4) * 8;
  const float* p = ws + O_P;
  const float* bc = ws + O_BCG;
  unsigned short* ah = (unsigned short*)(ws + dstH);
  unsigned short* al = (unsigned short*)(ws + dstL);
  float wv[NE];
#pragma unroll
  for (int e = 0; e < NE; ++e) wv[e] = bc[b * NE + e];
  float s[8] = {};
#pragma unroll
  for (int e = 0; e < NE; ++e) {
    const float* pr = p + (size_t)e * 262144 + (size_t)b * HH + k0;
    float4 p0 = *(const float4*)pr, p1 = *(const float4*)(pr + 4);
    const float* er = eb + e * HH + k0;
    float4 e0 = *(const float4*)er, e1 = *(const float4*)(er + 4);
    s[0] = fmaf(wv[e], p0.x + e0.x, s[0]);
    s[1] = fmaf(wv[e], p0.y + e0.y, s[1]);
    s[2] = fmaf(wv[e], p0.z + e0.z, s[2]);
    s[3] = fmaf(wv[e], p0.w + e0.w, s[3]);
    s[4] = fmaf(wv[e], p1.x + e1.x, s[4]);
    s[5] = fmaf(wv[e], p1.y + e1.y, s[5]);
    s[6] = fmaf(wv[e], p1.z + e1.z, s[6]);
    s[7] = fmaf(wv[e], p1.w + e1.w, s[7]);
  }
  us8 H, L;
#pragma unroll
  for (int j = 0; j < 8; ++j) {
    float v = eluf(s[j]);
    unsigned short h, lo; split_bf16(v, h, lo);
    H[j] = h; L[j] = lo;
  }
  *(us8*)(ah + (size_t)gid * 8) = H;
  *(us8*)(al + (size_t)gid * 8) = L;
}

// ================= comb3: out = sum_e bc*(p3+eb3) =================
__global__ __launch_bounds__(256) void k_comb3(const float* __restrict__ eb3,
    float* __restrict__ ws, float* __restrict__ out) {
  int gid = blockIdx.x * 256 + threadIdx.x;   // 65536 = 1024 x 64
  int b = gid >> 6, o = gid & 63;
  if (o >= DOUT) return;
  const float* p3 = ws + O_P;
  const float* bc = ws + O_BCG;
  float s = 0.f;
#pragma unroll
  for (int e = 0; e < NE; ++e)
    s = fmaf(bc[b * NE + e], p3[(size_t)e * 65536 + (size_t)b * 64 + o] + eb3[e * DOUT + o], s);
  out[(size_t)b * DOUT + o] = s;
}

extern "C" void kernel_launch(void* const* d_in, const int* in_sizes, int n_in,
                              void* d_out, int out_size, void* d_ws, size_t ws_size,
                              hipStream_t stream) {
  const float* x      = (const float*)d_in[0];
  const float* w1     = (const float*)d_in[1];
  const float* b1     = (const float*)d_in[2];
  const float* gamma1 = (const float*)d_in[3];
  const float* beta1  = (const float*)d_in[4];
  const float* w2     = (const float*)d_in[5];
  const float* b2     = (const float*)d_in[6];
  const float* gamma2 = (const float*)d_in[7];
  const float* beta2  = (const float*)d_in[8];
  const float* gw1    = (const float*)d_in[9];
  const float* gb1    = (const float*)d_in[10];
  const float* gw2    = (const float*)d_in[11];
  const float* gb2    = (const float*)d_in[12];
  const float* gw3    = (const float*)d_in[13];
  const float* gb3    = (const float*)d_in[14];
  const float* ew1    = (const float*)d_in[15];
  const float* eb1    = (const float*)d_in[16];
  const float* ew2    = (const float*)d_in[17];
  const float* eb2    = (const float*)d_in[18];
  const float* ew3    = (const float*)d_in[19];
  const float* eb3    = (const float*)d_in[20];
  float* wsf  = (float*)d_ws;
  float* outp = (float*)d_out;

  k_prep<<<516, 256, 0, stream>>>(x, w1, ew1, ew2, ew3, wsf);
  k_enc1<<<64, 256, 0, stream>>>(b1, wsf);
  k_enc2<<<64, 256, 0, stream>>>(gamma1, beta1, w2, b2, wsf);
  k_gate<<<64, 256, 0, stream>>>(gamma2, beta2, gw1, gb1, gw2, gb2, gw3, gb3, wsf);
  k_gen1<<<dim3(64, 8), 256, 0, stream>>>(wsf);
  k_comb<<<128, 256, 0, stream>>>(eb1, wsf, O_A1H, O_A1L);
  k_gen2<<<dim3(64, 8), 256, 0, stream>>>(wsf);
  k_comb<<<128, 256, 0, stream>>>(eb2, wsf, O_A2H, O_A2L);
  k_gen3<<<dim3(64, 2), 256, 0, stream>>>(wsf);
  k_comb3<<<256, 256, 0, stream>>>(eb3, wsf, outp);
}